// Round 5
// baseline (98.538 us; speedup 1.0000x reference)
//
#include <hip/hip_runtime.h>

// CARAFE++ downsample: B=8, C=128, H=W=160, stride 2 -> HD=WD=80
#define B   8
#define C   128
#define H   160
#define W   160
#define HW  (H*W)       // 25600
#define CM  16
#define KC  25
#define HD  80
#define WD  80
#define HWD (HD*WD)     // 6400

// ---- stage 1: 1x1 conv 128->16, 2 pixels/thread, ci unrolled x16 ----
__global__ __launch_bounds__(256) void compress_k(const float* __restrict__ x,
                                                  const float* __restrict__ wc,
                                                  float* __restrict__ comp) {
    int gid = blockIdx.x * 256 + threadIdx.x;       // 0 .. B*HW/2-1
    int b   = gid / (HW / 2);
    int pos = (gid % (HW / 2)) * 2;
    const float* xb = x + (size_t)b * C * HW + pos;
    float2 acc[CM];
#pragma unroll
    for (int co = 0; co < CM; ++co) acc[co] = make_float2(0.f, 0.f);
    for (int ci0 = 0; ci0 < C; ci0 += 16) {
        float2 v[16];
#pragma unroll
        for (int u = 0; u < 16; ++u)                // 16 loads in flight
            v[u] = *reinterpret_cast<const float2*>(xb + (size_t)(ci0 + u) * HW);
#pragma unroll
        for (int u = 0; u < 16; ++u)
#pragma unroll
            for (int co = 0; co < CM; ++co) {
                float wv = wc[co * C + ci0 + u];    // uniform -> s_load
                acc[co].x = fmaf(v[u].x, wv, acc[co].x);
                acc[co].y = fmaf(v[u].y, wv, acc[co].y);
            }
    }
    float* cb = comp + (size_t)b * CM * HW + pos;
#pragma unroll
    for (int co = 0; co < CM; ++co)
        *reinterpret_cast<float2*>(cb + co * HW) = acc[co];
}

// ---- stage 2: 3x3 s2 conv 16->25 + softmax; ci split across 4 waves ----
__global__ __launch_bounds__(256) void encoder_k(const float* __restrict__ comp,
                                                 const float* __restrict__ we,
                                                 float* __restrict__ ker) {
    __shared__ float part[4][KC][64];
    int lane = threadIdx.x & 63;
    int sub  = __builtin_amdgcn_readfirstlane(threadIdx.x >> 6);  // wave id, uniform
    int p  = blockIdx.x * 64 + lane;                // pixel 0..51199
    int b  = p / HWD;
    int r2 = p % HWD;
    int hd = r2 / WD;
    int wd = r2 % WD;
    const float* cb = comp + (size_t)b * CM * HW;
    float acc[KC];
#pragma unroll
    for (int ko = 0; ko < KC; ++ko) acc[ko] = 0.f;
#pragma unroll
    for (int cii = 0; cii < 4; ++cii) {
        int ci = sub * 4 + cii;                     // uniform -> we stays s_load
#pragma unroll
        for (int kh = 0; kh < 3; ++kh) {
            int r    = 2 * hd + kh - 1;
            bool rok = (unsigned)r < H;
            int rc   = min(max(r, 0), H - 1);
#pragma unroll
            for (int kw = 0; kw < 3; ++kw) {
                int c0  = 2 * wd + kw - 1;
                bool ok = rok && ((unsigned)c0 < W);
                int cc  = min(max(c0, 0), W - 1);
                float cv = cb[(size_t)ci * HW + rc * W + cc];
                cv = ok ? cv : 0.f;
#pragma unroll
                for (int ko = 0; ko < KC; ++ko)
                    acc[ko] = fmaf(cv, we[((ko * CM + ci) * 3 + kh) * 3 + kw], acc[ko]);
            }
        }
    }
#pragma unroll
    for (int ko = 0; ko < KC; ++ko) part[sub][ko][lane] = acc[ko];
    __syncthreads();
    if (threadIdx.x < 64) {
        float a[KC];
#pragma unroll
        for (int ko = 0; ko < KC; ++ko)
            a[ko] = (part[0][ko][lane] + part[1][ko][lane]) +
                    (part[2][ko][lane] + part[3][ko][lane]);
        float m = a[0];
#pragma unroll
        for (int ko = 1; ko < KC; ++ko) m = fmaxf(m, a[ko]);
        float s = 0.f;
#pragma unroll
        for (int ko = 0; ko < KC; ++ko) { a[ko] = __expf(a[ko] - m); s += a[ko]; }
        float inv = 1.f / s;
        float* kp = ker + (size_t)b * KC * HWD + hd * WD + wd;
#pragma unroll
        for (int ko = 0; ko < KC; ++ko) kp[ko * HWD] = a[ko] * inv;
    }
}

// ---- stage 3: 5x5 s2 reassembly, shuffle-window version ----
// wave = 1 output row (lanes 0..39 = wd-pairs, 40..63 clamped+store-masked).
// Per row of the 5x5 window each lane loads ONE aligned float4 (cols
// 4pr..4pr+3, union-dense across lanes); edge cols come from neighbor lanes
// via shfl (w0,w1 = lane-1's .z/.w ; w6 = lane+1's .x). Row-boundary lanes'
// foreign taps are exactly the zero-masked OOB taps. Masked 25-tap kernel
// weights are built ONCE per block and amortized over an 8-channel loop.
__global__ __launch_bounds__(256) void reassemble_k(const float* __restrict__ x,
                                                    const float* __restrict__ ker,
                                                    float* __restrict__ out) {
    int bid  = blockIdx.x;
    int cg   = bid & 15;                 // 8-channel group, fastest -> shares ker in L2
    int t    = bid >> 4;
    int hq   = t % 20;                   // hd quad
    int b    = t / 20;
    int wave = threadIdx.x >> 6;
    int lane = threadIdx.x & 63;
    int hd   = hq * 4 + wave;
    int prc  = min(lane, 39);            // clamped wd-pair (lanes 40..63 duplicate 39)
    bool act = lane < 40;
    int wd0  = prc * 2;

    // masked kernel weights for (hd, wd0, wd0+1) — once per 8 channels
    const float* kb = ker + (size_t)b * KC * HWD + hd * WD + wd0;
    float k0m[KC], k1m[KC];
    bool rv[5];
#pragma unroll
    for (int i = 0; i < 5; ++i) rv[i] = (unsigned)(2 * hd + i - 2) < H;
    bool c0lo = (prc > 0);               // out0 taps j=0,1 valid?
    bool c1hi = (prc < 39);              // out1 tap  j=4  valid?
#pragma unroll
    for (int i = 0; i < 5; ++i)
#pragma unroll
        for (int j = 0; j < 5; ++j) {
            float2 kv = *reinterpret_cast<const float2*>(kb + (i * 5 + j) * HWD);
            k0m[i * 5 + j] = (rv[i] && (j >= 2 || c0lo)) ? kv.x : 0.f;
            k1m[i * 5 + j] = (rv[i] && (j <= 3 || c1hi)) ? kv.y : 0.f;
        }

    // clamped row offsets; every address in-bounds, 16B aligned
    int off[5];
#pragma unroll
    for (int i = 0; i < 5; ++i)
        off[i] = min(max(2 * hd + i - 2, 0), H - 1) * W + 4 * prc;

    const float* xc = x + (size_t)(b * C + cg * 8) * HW;
    float* ob = out + ((size_t)(b * C + cg * 8) * HD + hd) * WD + wd0;
#pragma unroll 2
    for (int cc = 0; cc < 8; ++cc) {
        float4 bq[5];
#pragma unroll
        for (int i = 0; i < 5; ++i)
            bq[i] = *reinterpret_cast<const float4*>(xc + off[i]);
        float acc0 = 0.f, acc1 = 0.f;
#pragma unroll
        for (int i = 0; i < 5; ++i) {
            float w0 = __shfl_up(bq[i].z, 1);       // col 4pr-2 (lane 0: masked)
            float w1 = __shfl_up(bq[i].w, 1);       // col 4pr-1 (lane 0: masked)
            float w6 = __shfl_down(bq[i].x, 1);     // col 4pr+4 (lane 39: masked)
            acc0 = fmaf(w0,      k0m[i * 5 + 0], acc0);
            acc0 = fmaf(w1,      k0m[i * 5 + 1], acc0);
            acc0 = fmaf(bq[i].x, k0m[i * 5 + 2], acc0);
            acc0 = fmaf(bq[i].y, k0m[i * 5 + 3], acc0);
            acc0 = fmaf(bq[i].z, k0m[i * 5 + 4], acc0);
            acc1 = fmaf(bq[i].x, k1m[i * 5 + 0], acc1);
            acc1 = fmaf(bq[i].y, k1m[i * 5 + 1], acc1);
            acc1 = fmaf(bq[i].z, k1m[i * 5 + 2], acc1);
            acc1 = fmaf(bq[i].w, k1m[i * 5 + 3], acc1);
            acc1 = fmaf(w6,      k1m[i * 5 + 4], acc1);
        }
        if (act) *reinterpret_cast<float2*>(ob) = make_float2(acc0, acc1);
        xc += HW;
        ob += HWD;
    }
}

extern "C" void kernel_launch(void* const* d_in, const int* in_sizes, int n_in,
                              void* d_out, int out_size, void* d_ws, size_t ws_size,
                              hipStream_t stream) {
    const float* x  = (const float*)d_in[0];
    const float* wc = (const float*)d_in[1];
    const float* we = (const float*)d_in[2];
    float* out  = (float*)d_out;
    float* comp = (float*)d_ws;                       // B*CM*HW   = 3,276,800 f32
    float* ker  = comp + (size_t)B * CM * HW;         // B*KC*HWD  = 1,280,000 f32

    compress_k  <<<(B * HW / 2) / 256, 256, 0, stream>>>(x, wc, comp);   // 400 blocks
    encoder_k   <<<(B * HWD) / 64,     256, 0, stream>>>(comp, we, ker); // 800 blocks
    reassemble_k<<<8 * 20 * 16,        256, 0, stream>>>(x, ker, out);   // 2560 blocks
}